// Round 3
// baseline (1456.815 us; speedup 1.0000x reference)
//
#include <hip/hip_runtime.h>
#include <math.h>

// ---------------------------------------------------------------------------
// GTAN2. R3: k_mm gains register prefetch pipelining (hide global latency
// under FMA window); hlin stored bf16-only (halves gather traffic, kills the
// fp32 bufA write); k_agg gather unrolled x4 with bf16 rows.
// ---------------------------------------------------------------------------

__device__ __forceinline__ float lrelu02(float v) { return v > 0.f ? v : 0.2f * v; }

__device__ __forceinline__ float2 bf2f2(unsigned int v) {
    return make_float2(__uint_as_float(v << 16), __uint_as_float(v & 0xffff0000u));
}
__device__ __forceinline__ unsigned int f2bf(float f) {
    unsigned int u = __float_as_uint(f);
    u += 0x7fffu + ((u >> 16) & 1u);
    return u >> 16;
}

// ---------------- CSR build ----------------
__global__ __launch_bounds__(256) void k_count(const int* __restrict__ s, int* __restrict__ cnt, int E) {
    int e = blockIdx.x * 256 + threadIdx.x;
    if (e < E) atomicAdd(&cnt[s[e]], 1);
}

__global__ __launch_bounds__(256) void k_scan1(const int* __restrict__ cnt, int* __restrict__ bs, int N) {
    __shared__ int sh[256];
    int idx = blockIdx.x * 256 + threadIdx.x;
    sh[threadIdx.x] = (idx < N) ? cnt[idx] : 0;
    __syncthreads();
#pragma unroll
    for (int off = 128; off; off >>= 1) {
        if (threadIdx.x < off) sh[threadIdx.x] += sh[threadIdx.x + off];
        __syncthreads();
    }
    if (threadIdx.x == 0) bs[blockIdx.x] = sh[0];
}

__global__ __launch_bounds__(256) void k_scan2(int* __restrict__ bs, int G) {
    __shared__ int sh[256];
    int t = threadIdx.x;
    int v = (t < G) ? bs[t] : 0;
    sh[t] = v;
    __syncthreads();
    int val = v;
#pragma unroll
    for (int off = 1; off < 256; off <<= 1) {
        int o = (t >= off) ? sh[t - off] : 0;
        __syncthreads();
        val += o; sh[t] = val;
        __syncthreads();
    }
    if (t < G) bs[t] = val - v;  // exclusive
}

__global__ __launch_bounds__(256) void k_scan3(const int* __restrict__ cnt, const int* __restrict__ bs,
                                               int* __restrict__ rp, int N) {
    __shared__ int sh[256];
    int t = threadIdx.x;
    int idx = blockIdx.x * 256 + t;
    int v = (idx < N) ? cnt[idx] : 0;
    sh[t] = v;
    __syncthreads();
    int val = v;
#pragma unroll
    for (int off = 1; off < 256; off <<= 1) {
        int o = (t >= off) ? sh[t - off] : 0;
        __syncthreads();
        val += o; sh[t] = val;
        __syncthreads();
    }
    if (idx <= N) rp[idx] = val - v + bs[blockIdx.x];
}

__global__ __launch_bounds__(256) void k_scatter(const int* __restrict__ s, const int* __restrict__ t,
                                                 const int* __restrict__ rp, int* __restrict__ cursor,
                                                 int* __restrict__ t_sorted, int E) {
    int e = blockIdx.x * 256 + threadIdx.x;
    if (e < E) {
        int u = s[e];
        int pos = atomicAdd(&cursor[u], 1);
        t_sorted[rp[u] + pos] = t[e];
    }
}

// ---------------- GEMM: Y = X @ W^T + b, 128x128 tile, 8x8 micro, pipelined ----
// Dual-source: blocks [0,nblk0) use X0 -> fp32 Y0 (+dots dA0->oA0, dB0->oB0),
// blocks [nblk0,..) use X1 -> bf16 Ybf1 only (+dot dA1->oA1).
#define BK 32
#define LDSP 132

__global__ __launch_bounds__(256) void k_mm(
    const float* __restrict__ X0, const float* __restrict__ X1, int nblk0,
    const float* __restrict__ W, const float* __restrict__ bias,
    float* __restrict__ Y0, unsigned short* __restrict__ Ybf1,
    int N, int K, int ncols, int ldy, int relu,
    const float* __restrict__ dA0, float* __restrict__ oA0,
    const float* __restrict__ dB0, float* __restrict__ oB0,
    const float* __restrict__ dA1, float* __restrict__ oA1) {
    __shared__ float Xs[BK][LDSP];
    __shared__ float Ws[BK][LDSP];
    const int tid = threadIdx.x;
    const bool second = (int)blockIdx.x >= nblk0;
    const int bx = second ? blockIdx.x - nblk0 : blockIdx.x;
    const float* X = second ? X1 : X0;
    float* Y = second ? nullptr : Y0;
    unsigned short* Yb = second ? Ybf1 : nullptr;
    const float* dA = second ? dA1 : dA0;
    float* oA = second ? oA1 : oA0;
    const float* dB = second ? nullptr : dB0;
    float* oB = second ? nullptr : oB0;
    const int r0 = bx * 128;
    const int tx = tid & 15, ty = tid >> 4;
    const int srow = tid >> 1;          // 0..127
    const int shalf = (tid & 1) << 4;   // 0 or 16

    const int gr = r0 + srow;
    const bool xok = gr < N;
    const bool wok = srow < ncols;
    const float4 z4 = make_float4(0.f, 0.f, 0.f, 0.f);
    const float* xp = X + (size_t)gr * K + shalf;
    const float* wp = W + (size_t)srow * K + shalf;

    float4 xv[4], wv[4];
#pragma unroll
    for (int q = 0; q < 4; ++q) {
        xv[q] = xok ? *(const float4*)(xp + q * 4) : z4;
        wv[q] = wok ? *(const float4*)(wp + q * 4) : z4;
    }

    float acc[8][8] = {};
#define FMAROW(i, s) \
    acc[i][0] = fmaf(s, b0.x, acc[i][0]); acc[i][1] = fmaf(s, b0.y, acc[i][1]); \
    acc[i][2] = fmaf(s, b0.z, acc[i][2]); acc[i][3] = fmaf(s, b0.w, acc[i][3]); \
    acc[i][4] = fmaf(s, b1.x, acc[i][4]); acc[i][5] = fmaf(s, b1.y, acc[i][5]); \
    acc[i][6] = fmaf(s, b1.z, acc[i][6]); acc[i][7] = fmaf(s, b1.w, acc[i][7]);

    for (int kb = 0; kb < K; kb += BK) {
        if (kb) __syncthreads();
#pragma unroll
        for (int q = 0; q < 4; ++q) {
            Xs[shalf + q * 4 + 0][srow] = xv[q].x;
            Xs[shalf + q * 4 + 1][srow] = xv[q].y;
            Xs[shalf + q * 4 + 2][srow] = xv[q].z;
            Xs[shalf + q * 4 + 3][srow] = xv[q].w;
            Ws[shalf + q * 4 + 0][srow] = wv[q].x;
            Ws[shalf + q * 4 + 1][srow] = wv[q].y;
            Ws[shalf + q * 4 + 2][srow] = wv[q].z;
            Ws[shalf + q * 4 + 3][srow] = wv[q].w;
        }
        __syncthreads();
        if (kb + BK < K) {  // prefetch next K-tile while computing this one
            xp += BK; wp += BK;
#pragma unroll
            for (int q = 0; q < 4; ++q) {
                xv[q] = xok ? *(const float4*)(xp + q * 4) : z4;
                wv[q] = wok ? *(const float4*)(wp + q * 4) : z4;
            }
        }
#pragma unroll
        for (int k = 0; k < BK; ++k) {
            const float4 a0 = *(const float4*)&Xs[k][ty * 8];
            const float4 a1 = *(const float4*)&Xs[k][ty * 8 + 4];
            const float4 b0 = *(const float4*)&Ws[k][tx * 4];
            const float4 b1 = *(const float4*)&Ws[k][tx * 4 + 64];
            FMAROW(0, a0.x) FMAROW(1, a0.y) FMAROW(2, a0.z) FMAROW(3, a0.w)
            FMAROW(4, a1.x) FMAROW(5, a1.y) FMAROW(6, a1.z) FMAROW(7, a1.w)
        }
    }
#undef FMAROW

    const int cola = tx * 4, colb = 64 + tx * 4;
    const bool haveb = colb < ncols;
    const float4 bva = *(const float4*)(bias + cola);
    const float4 bvb = haveb ? *(const float4*)(bias + colb) : z4;
    const bool doA = dA != nullptr, doB = dB != nullptr;
    float4 dAa = z4, dAb = z4, dBa = z4, dBb = z4;
    if (doA) { dAa = *(const float4*)(dA + cola); dAb = *(const float4*)(dA + colb); }
    if (doB) { dBa = *(const float4*)(dB + cola); dBb = *(const float4*)(dB + colb); }

#pragma unroll
    for (int i = 0; i < 8; ++i) {
        int r = r0 + ty * 8 + i;
        if (r >= N) continue;  // uniform within each 16-lane tx group
        float va[4], vb[4];
        va[0] = acc[i][0] + bva.x; va[1] = acc[i][1] + bva.y;
        va[2] = acc[i][2] + bva.z; va[3] = acc[i][3] + bva.w;
        vb[0] = acc[i][4] + bvb.x; vb[1] = acc[i][5] + bvb.y;
        vb[2] = acc[i][6] + bvb.z; vb[3] = acc[i][7] + bvb.w;
        float pA = 0.f, pB = 0.f;
        if (doA) {
            pA = va[0]*dAa.x + va[1]*dAa.y + va[2]*dAa.z + va[3]*dAa.w
               + vb[0]*dAb.x + vb[1]*dAb.y + vb[2]*dAb.z + vb[3]*dAb.w;
        }
        if (doB) {
            pB = va[0]*dBa.x + va[1]*dBa.y + va[2]*dBa.z + va[3]*dBa.w
               + vb[0]*dBb.x + vb[1]*dBb.y + vb[2]*dBb.z + vb[3]*dBb.w;
        }
        if (relu) {
#pragma unroll
            for (int j = 0; j < 4; ++j) { va[j] = fmaxf(va[j], 0.f); vb[j] = fmaxf(vb[j], 0.f); }
        }
        if (Y) {
            *(float4*)(Y + (size_t)r * ldy + cola) = make_float4(va[0], va[1], va[2], va[3]);
            if (haveb) *(float4*)(Y + (size_t)r * ldy + colb) = make_float4(vb[0], vb[1], vb[2], vb[3]);
        }
        if (Yb) {
            uint2 pa, pb;
            pa.x = f2bf(va[0]) | (f2bf(va[1]) << 16);
            pa.y = f2bf(va[2]) | (f2bf(va[3]) << 16);
            *(uint2*)(Yb + (size_t)r * 128 + cola) = pa;
            if (haveb) {
                pb.x = f2bf(vb[0]) | (f2bf(vb[1]) << 16);
                pb.y = f2bf(vb[2]) | (f2bf(vb[3]) << 16);
                *(uint2*)(Yb + (size_t)r * 128 + colb) = pb;
            }
        }
        if (doA) {
#pragma unroll
            for (int m = 1; m < 16; m <<= 1) {
                pA += __shfl_xor(pA, m, 64);
                if (doB) pB += __shfl_xor(pB, m, 64);
            }
            if (tx == 0) {
                oA[r] = pA;
                if (doB) oB[r] = pB;
            }
        }
    }
}

// ---------------- aggregation: fused w1/w2 + bf16 gather + elu ----------------
__global__ __launch_bounds__(64) void k_agg(
    const float* __restrict__ xnew, const unsigned short* __restrict__ hbf,
    const float* __restrict__ x1a, const float* __restrict__ xa2a,
    const float* __restrict__ h1a, const int* __restrict__ rp,
    const int* __restrict__ ts, float* __restrict__ hout, int N) {
    int u = blockIdx.x;
    int lane = threadIdx.x;
    int l2 = lane << 1;
    float x1u = x1a[u];
    float w2 = expf(lrelu02(x1u + xa2a[u]));
    float2 xr = *(const float2*)(xnew + (size_t)u * 128 + l2);
    float accx = w2 * xr.x, accy = w2 * xr.y;
    float div = w2;
    int p0 = rp[u], p1 = rp[u + 1];
    for (int base = p0; base < p1; base += 64) {
        int e = base + lane;
        int tv = 0;
        float wv = 0.f;
        if (e < p1) {
            tv = ts[e];
            wv = expf(lrelu02(x1u + h1a[tv]));
        }
        int m = p1 - base; if (m > 64) m = 64;
        int j = 0;
        for (; j + 4 <= m; j += 4) {
            float w0 = __shfl(wv, j, 64),  w1 = __shfl(wv, j + 1, 64);
            float w2e = __shfl(wv, j + 2, 64), w3 = __shfl(wv, j + 3, 64);
            int t0 = __shfl(tv, j, 64),  t1 = __shfl(tv, j + 1, 64);
            int t2 = __shfl(tv, j + 2, 64), t3 = __shfl(tv, j + 3, 64);
            unsigned int h0 = *(const unsigned int*)(hbf + (size_t)t0 * 128 + l2);
            unsigned int h1 = *(const unsigned int*)(hbf + (size_t)t1 * 128 + l2);
            unsigned int h2 = *(const unsigned int*)(hbf + (size_t)t2 * 128 + l2);
            unsigned int h3 = *(const unsigned int*)(hbf + (size_t)t3 * 128 + l2);
            float2 f0 = bf2f2(h0), f1 = bf2f2(h1), f2 = bf2f2(h2), f3 = bf2f2(h3);
            accx = fmaf(w0, f0.x, accx); accy = fmaf(w0, f0.y, accy);
            accx = fmaf(w1, f1.x, accx); accy = fmaf(w1, f1.y, accy);
            accx = fmaf(w2e, f2.x, accx); accy = fmaf(w2e, f2.y, accy);
            accx = fmaf(w3, f3.x, accx); accy = fmaf(w3, f3.y, accy);
            div += (w0 + w1) + (w2e + w3);
        }
        for (; j < m; ++j) {
            float w = __shfl(wv, j, 64);
            int tt = __shfl(tv, j, 64);
            float2 f = bf2f2(*(const unsigned int*)(hbf + (size_t)tt * 128 + l2));
            accx = fmaf(w, f.x, accx); accy = fmaf(w, f.y, accy);
            div += w;
        }
    }
    float ox = accx / div, oy = accy / div;
    ox = ox > 0.f ? ox : expf(ox) - 1.f;
    oy = oy > 0.f ? oy : expf(oy) - 1.f;
    *(float2*)(hout + (size_t)u * 128 + l2) = make_float2(ox, oy);
}

// ---------------- launch ----------------
extern "C" void kernel_launch(void* const* d_in, const int* in_sizes, int n_in,
                              void* d_out, int out_size, void* d_ws, size_t ws_size,
                              hipStream_t stream) {
    const float* x_in = (const float*)d_in[0];
    const int*   s    = (const int*)d_in[1];
    const int*   t    = (const int*)d_in[2];
    const float* fc1W = (const float*)d_in[3];
    const float* fc1b = (const float*)d_in[4];
    const float* fcsW = (const float*)d_in[5];
    const float* fcsb = (const float*)d_in[6];
    const float* a1   = (const float*)d_in[7];
    const float* a2   = (const float*)d_in[8];
    const float* fc2W = (const float*)d_in[9];
    const float* fc2b = (const float*)d_in[10];

    const int N = in_sizes[0] / 256;  // 50000
    const int E = in_sizes[1];        // 800000
    const int G = (N + 255) / 256;    // 196 scan blocks
    const int NB = (N + 127) / 128;   // 391 gemm row-blocks

    char* ws = (char*)d_ws;
    size_t off = 0;
    auto alloc = [&](size_t bytes) -> void* {
        void* p = ws + off;
        off += (bytes + 255) & ~(size_t)255;
        return p;
    };
    float* xbuf  = (float*)alloc((size_t)N * 128 * 4);
    float* bufB  = (float*)alloc((size_t)N * 128 * 4);          // h state
    float* xnew  = (float*)alloc((size_t)N * 128 * 4);
    unsigned short* hbf = (unsigned short*)alloc((size_t)N * 128 * 2);  // hlin bf16
    float* x1a   = (float*)alloc((size_t)N * 4);
    float* xa2a  = (float*)alloc((size_t)N * 4);
    float* h1a   = (float*)alloc((size_t)N * 4);
    int* row_ptr  = (int*)alloc((size_t)(N + 1) * 4);
    int* cnt      = (int*)alloc((size_t)N * 4);
    int* bsums    = (int*)alloc((size_t)256 * 4);
    int* t_sorted = (int*)alloc((size_t)E * 4);

    // CSR build
    hipMemsetAsync(cnt, 0, (size_t)N * 4, stream);
    k_count<<<(E + 255) / 256, 256, 0, stream>>>(s, cnt, E);
    k_scan1<<<G, 256, 0, stream>>>(cnt, bsums, N);
    k_scan2<<<1, 256, 0, stream>>>(bsums, G);
    k_scan3<<<G, 256, 0, stream>>>(cnt, bsums, row_ptr, N);
    hipMemsetAsync(cnt, 0, (size_t)N * 4, stream);
    k_scatter<<<(E + 255) / 256, 256, 0, stream>>>(s, t, row_ptr, cnt, t_sorted, E);

    // fc1 + relu
    k_mm<<<NB, 256, 0, stream>>>(x_in, nullptr, NB, fc1W, fc1b, xbuf, nullptr,
                                 N, 256, 128, 128, 1,
                                 nullptr, nullptr, nullptr, nullptr, nullptr, nullptr);

    // hops
    const float* hsrc = xbuf;
    for (int i = 0; i < 10; ++i) {
        const float* W   = fcsW + (size_t)i * 128 * 128;
        const float* b   = fcsb + (size_t)i * 128;
        const float* a1i = a1 + (size_t)i * 128;
        const float* a2i = a2 + (size_t)i * 128;
        k_mm<<<2 * NB, 256, 0, stream>>>(xbuf, hsrc, NB, W, b, xnew, hbf,
                                         N, 128, 128, 128, 0,
                                         a1i, x1a, a2i, xa2a, a2i, h1a);
        k_agg<<<N, 64, 0, stream>>>(xnew, hbf, x1a, xa2a, h1a, row_ptr, t_sorted, bufB, N);
        hsrc = bufB;
    }

    // fc2
    k_mm<<<NB, 256, 0, stream>>>(bufB, nullptr, NB, fc2W, fc2b, (float*)d_out, nullptr,
                                 N, 128, 64, 64, 0,
                                 nullptr, nullptr, nullptr, nullptr, nullptr, nullptr);
}

// Round 4
// 1268.955 us; speedup vs baseline: 1.1480x; 1.1480x over previous
//
#include <hip/hip_runtime.h>
#include <math.h>

// ---------------------------------------------------------------------------
// GTAN2 R4: hop GEMMs via split-bf16 MFMA (3-term: XhWh + XhWl + XlWh).
// hi/lo bf16 planes produced by fc1/k_agg epilogues + W-split kernel, so the
// hot GEMM stages pure bf16 into XOR-swizzled LDS and runs
// mfma_f32_16x16x32_bf16. fc1/fc2 stay fp32 (R2 structure, prefetch reverted).
// k_agg: 4 nodes per 256-thread block.
// ---------------------------------------------------------------------------

typedef __attribute__((ext_vector_type(8))) short short8;
typedef __attribute__((ext_vector_type(4))) float f32x4;
#define MFMA16 __builtin_amdgcn_mfma_f32_16x16x32_bf16

__device__ __forceinline__ float lrelu02(float v) { return v > 0.f ? v : 0.2f * v; }

__device__ __forceinline__ float2 bf2f2(unsigned int v) {
    return make_float2(__uint_as_float(v << 16), __uint_as_float(v & 0xffff0000u));
}
__device__ __forceinline__ unsigned int f2bf(float f) {  // RNE bf16
    unsigned int u = __float_as_uint(f);
    u += 0x7fffu + ((u >> 16) & 1u);
    return u >> 16;
}
__device__ __forceinline__ float hi_part(float f) {  // truncate mantissa to bf16
    return __uint_as_float(__float_as_uint(f) & 0xffff0000u);
}

// ---------------- CSR build ----------------
__global__ __launch_bounds__(256) void k_count(const int* __restrict__ s, int* __restrict__ cnt, int E) {
    int e = blockIdx.x * 256 + threadIdx.x;
    if (e < E) atomicAdd(&cnt[s[e]], 1);
}

__global__ __launch_bounds__(256) void k_scan1(const int* __restrict__ cnt, int* __restrict__ bs, int N) {
    __shared__ int sh[256];
    int idx = blockIdx.x * 256 + threadIdx.x;
    sh[threadIdx.x] = (idx < N) ? cnt[idx] : 0;
    __syncthreads();
#pragma unroll
    for (int off = 128; off; off >>= 1) {
        if (threadIdx.x < off) sh[threadIdx.x] += sh[threadIdx.x + off];
        __syncthreads();
    }
    if (threadIdx.x == 0) bs[blockIdx.x] = sh[0];
}

__global__ __launch_bounds__(256) void k_scan2(int* __restrict__ bs, int G) {
    __shared__ int sh[256];
    int t = threadIdx.x;
    int v = (t < G) ? bs[t] : 0;
    sh[t] = v;
    __syncthreads();
    int val = v;
#pragma unroll
    for (int off = 1; off < 256; off <<= 1) {
        int o = (t >= off) ? sh[t - off] : 0;
        __syncthreads();
        val += o; sh[t] = val;
        __syncthreads();
    }
    if (t < G) bs[t] = val - v;  // exclusive
}

__global__ __launch_bounds__(256) void k_scan3(const int* __restrict__ cnt, const int* __restrict__ bs,
                                               int* __restrict__ rp, int N) {
    __shared__ int sh[256];
    int t = threadIdx.x;
    int idx = blockIdx.x * 256 + t;
    int v = (idx < N) ? cnt[idx] : 0;
    sh[t] = v;
    __syncthreads();
    int val = v;
#pragma unroll
    for (int off = 1; off < 256; off <<= 1) {
        int o = (t >= off) ? sh[t - off] : 0;
        __syncthreads();
        val += o; sh[t] = val;
        __syncthreads();
    }
    if (idx <= N) rp[idx] = val - v + bs[blockIdx.x];
}

__global__ __launch_bounds__(256) void k_scatter(const int* __restrict__ s, const int* __restrict__ t,
                                                 const int* __restrict__ rp, int* __restrict__ cursor,
                                                 int* __restrict__ t_sorted, int E) {
    int e = blockIdx.x * 256 + threadIdx.x;
    if (e < E) {
        int u = s[e];
        int pos = atomicAdd(&cursor[u], 1);
        t_sorted[rp[u] + pos] = t[e];
    }
}

// ---------------- W split: fp32 -> (hi trunc-bf16, lo RNE-bf16) ----------------
__global__ __launch_bounds__(256) void k_wsplit(const float* __restrict__ W,
                                                unsigned short* __restrict__ Whi,
                                                unsigned short* __restrict__ Wlo, int total) {
    int i = blockIdx.x * 256 + threadIdx.x;
    if (i < total) {
        float f = W[i];
        unsigned int u = __float_as_uint(f);
        Whi[i] = (unsigned short)(u >> 16);
        Wlo[i] = (unsigned short)f2bf(f - __uint_as_float(u & 0xffff0000u));
    }
}

// ---------------- fp32 GEMM (fc1 / fc2): Y = X @ W^T + b ----------------
// Modes: input Xf fp32 OR (Xhi,Xlo) planes reconstructed; output Yf fp32 OR
// (Yhi,Ylo) split planes (with optional relu before split).
#define BKF 32
#define LDSP 132

__global__ __launch_bounds__(256) void k_mm(
    const float* __restrict__ Xf,
    const unsigned short* __restrict__ Xhi, const unsigned short* __restrict__ Xlo,
    const float* __restrict__ W, const float* __restrict__ bias,
    float* __restrict__ Yf, unsigned short* __restrict__ Yhi, unsigned short* __restrict__ Ylo,
    int N, int K, int ncols, int ldy, int relu) {
    __shared__ float Xs[BKF][LDSP];
    __shared__ float Ws[BKF][LDSP];
    const int tid = threadIdx.x;
    const int r0 = blockIdx.x * 128;
    const int tx = tid & 15, ty = tid >> 4;
    const int srow = tid >> 1;
    const int shalf = (tid & 1) << 4;
    const float4 z4 = make_float4(0.f, 0.f, 0.f, 0.f);

    float acc[8][8] = {};
    for (int kb = 0; kb < K; kb += BKF) {
        int gr = r0 + srow;
        bool xok = gr < N;
        bool wok = srow < ncols;
        float4 xv[4], wv[4];
        if (Xf) {
            const float* xp = Xf + (size_t)gr * K + kb + shalf;
#pragma unroll
            for (int q = 0; q < 4; ++q) xv[q] = xok ? *(const float4*)(xp + q * 4) : z4;
        } else {
            const unsigned short* hp = Xhi + (size_t)gr * K + kb + shalf;
            const unsigned short* lp = Xlo + (size_t)gr * K + kb + shalf;
#pragma unroll
            for (int q = 0; q < 4; ++q) {
                if (xok) {
                    uint2 h2 = *(const uint2*)(hp + q * 4);
                    uint2 l2 = *(const uint2*)(lp + q * 4);
                    xv[q].x = __uint_as_float(h2.x << 16) + __uint_as_float(l2.x << 16);
                    xv[q].y = __uint_as_float(h2.x & 0xffff0000u) + __uint_as_float(l2.x & 0xffff0000u);
                    xv[q].z = __uint_as_float(h2.y << 16) + __uint_as_float(l2.y << 16);
                    xv[q].w = __uint_as_float(h2.y & 0xffff0000u) + __uint_as_float(l2.y & 0xffff0000u);
                } else xv[q] = z4;
            }
        }
        const float* wp = W + (size_t)srow * K + kb + shalf;
#pragma unroll
        for (int q = 0; q < 4; ++q) wv[q] = wok ? *(const float4*)(wp + q * 4) : z4;
        __syncthreads();
#pragma unroll
        for (int q = 0; q < 4; ++q) {
            Xs[shalf + q * 4 + 0][srow] = xv[q].x;
            Xs[shalf + q * 4 + 1][srow] = xv[q].y;
            Xs[shalf + q * 4 + 2][srow] = xv[q].z;
            Xs[shalf + q * 4 + 3][srow] = xv[q].w;
            Ws[shalf + q * 4 + 0][srow] = wv[q].x;
            Ws[shalf + q * 4 + 1][srow] = wv[q].y;
            Ws[shalf + q * 4 + 2][srow] = wv[q].z;
            Ws[shalf + q * 4 + 3][srow] = wv[q].w;
        }
        __syncthreads();
#pragma unroll 8
        for (int k = 0; k < BKF; ++k) {
            const float4 a0 = *(const float4*)&Xs[k][ty * 8];
            const float4 a1 = *(const float4*)&Xs[k][ty * 8 + 4];
            const float4 b0 = *(const float4*)&Ws[k][tx * 4];
            const float4 b1 = *(const float4*)&Ws[k][tx * 4 + 64];
            const float av[8] = {a0.x, a0.y, a0.z, a0.w, a1.x, a1.y, a1.z, a1.w};
#pragma unroll
            for (int i = 0; i < 8; ++i) {
                acc[i][0] = fmaf(av[i], b0.x, acc[i][0]);
                acc[i][1] = fmaf(av[i], b0.y, acc[i][1]);
                acc[i][2] = fmaf(av[i], b0.z, acc[i][2]);
                acc[i][3] = fmaf(av[i], b0.w, acc[i][3]);
                acc[i][4] = fmaf(av[i], b1.x, acc[i][4]);
                acc[i][5] = fmaf(av[i], b1.y, acc[i][5]);
                acc[i][6] = fmaf(av[i], b1.z, acc[i][6]);
                acc[i][7] = fmaf(av[i], b1.w, acc[i][7]);
            }
        }
    }

    const int cola = tx * 4, colb = 64 + tx * 4;
    const bool haveb = colb < ncols;
    const float4 bva = *(const float4*)(bias + cola);
    const float4 bvb = haveb ? *(const float4*)(bias + colb) : z4;

#pragma unroll
    for (int i = 0; i < 8; ++i) {
        int r = r0 + ty * 8 + i;
        if (r >= N) continue;
        float va[4], vb[4];
        va[0] = acc[i][0] + bva.x; va[1] = acc[i][1] + bva.y;
        va[2] = acc[i][2] + bva.z; va[3] = acc[i][3] + bva.w;
        vb[0] = acc[i][4] + bvb.x; vb[1] = acc[i][5] + bvb.y;
        vb[2] = acc[i][6] + bvb.z; vb[3] = acc[i][7] + bvb.w;
        if (relu) {
#pragma unroll
            for (int j = 0; j < 4; ++j) { va[j] = fmaxf(va[j], 0.f); vb[j] = fmaxf(vb[j], 0.f); }
        }
        if (Yf) {
            *(float4*)(Yf + (size_t)r * ldy + cola) = make_float4(va[0], va[1], va[2], va[3]);
            if (haveb) *(float4*)(Yf + (size_t)r * ldy + colb) = make_float4(vb[0], vb[1], vb[2], vb[3]);
        }
        if (Yhi) {
            uint2 h, l;
            unsigned int u0 = __float_as_uint(va[0]), u1 = __float_as_uint(va[1]);
            unsigned int u2 = __float_as_uint(va[2]), u3 = __float_as_uint(va[3]);
            h.x = (u0 >> 16) | (u1 & 0xffff0000u);
            h.y = (u2 >> 16) | (u3 & 0xffff0000u);
            l.x = f2bf(va[0] - hi_part(va[0])) | (f2bf(va[1] - hi_part(va[1])) << 16);
            l.y = f2bf(va[2] - hi_part(va[2])) | (f2bf(va[3] - hi_part(va[3])) << 16);
            *(uint2*)(Yhi + (size_t)r * 128 + cola) = h;
            *(uint2*)(Ylo + (size_t)r * 128 + cola) = l;
            if (haveb) {
                unsigned int v0 = __float_as_uint(vb[0]), v1 = __float_as_uint(vb[1]);
                unsigned int v2 = __float_as_uint(vb[2]), v3 = __float_as_uint(vb[3]);
                h.x = (v0 >> 16) | (v1 & 0xffff0000u);
                h.y = (v2 >> 16) | (v3 & 0xffff0000u);
                l.x = f2bf(vb[0] - hi_part(vb[0])) | (f2bf(vb[1] - hi_part(vb[1])) << 16);
                l.y = f2bf(vb[2] - hi_part(vb[2])) | (f2bf(vb[3] - hi_part(vb[3])) << 16);
                *(uint2*)(Yhi + (size_t)r * 128 + colb) = h;
                *(uint2*)(Ylo + (size_t)r * 128 + colb) = l;
            }
        }
    }
}

// ---------------- hop GEMM: split-bf16 MFMA, 128x128 tile, dual-source -------
// src0 (blocks < nblk0): X planes -> xnew fp32 + dots(a1->oA0, a2->oB0)
// src1: H planes -> hlin bf16 + dot(a2->oA1)
__global__ __launch_bounds__(256) void k_mm_bf(
    const unsigned short* __restrict__ Xhi0, const unsigned short* __restrict__ Xlo0, int nblk0,
    const unsigned short* __restrict__ Xhi1, const unsigned short* __restrict__ Xlo1,
    const unsigned short* __restrict__ Whi, const unsigned short* __restrict__ Wlo,
    const float* __restrict__ bias,
    float* __restrict__ Yf0, unsigned short* __restrict__ Yb1, int N,
    const float* __restrict__ dA0, float* __restrict__ oA0,
    const float* __restrict__ dB0, float* __restrict__ oB0,
    const float* __restrict__ dA1, float* __restrict__ oA1) {
    // LDS: X tile [128 rows][8 granules x 16B] (g0-3 = hi k0..31, g4-7 = lo),
    // W tile same. XOR-swizzle granule with (row&7) -> conflict-floor reads.
    __shared__ unsigned short lds[2 * 128 * 64];  // 32 KB
    unsigned short* Xs = lds;
    unsigned short* Wt = lds + 128 * 64;

    const int tid = threadIdx.x;
    const bool second = (int)blockIdx.x >= nblk0;
    const int bx = second ? (int)blockIdx.x - nblk0 : (int)blockIdx.x;
    const int r0 = bx * 128;
    const int srow = tid & 127;
    const int splane = tid >> 7;  // 0 = hi, 1 = lo
    const unsigned short* Xp = second ? (splane ? Xlo1 : Xhi1) : (splane ? Xlo0 : Xhi0);
    const unsigned short* Wp = splane ? Wlo : Whi;
    const int xrow = r0 + srow;
    const bool xok = xrow < N;

    const int lane = tid & 63;
    const int w = tid >> 6;
    const int wr = (w >> 1) * 64, wc = (w & 1) * 64;
    const int frow = lane & 15;
    const int fk = lane >> 4;     // k-granule 0..3
    const int q4 = lane >> 4;

    f32x4 acc[4][4];
#pragma unroll
    for (int i = 0; i < 4; ++i)
#pragma unroll
        for (int j = 0; j < 4; ++j) acc[i][j] = (f32x4){0.f, 0.f, 0.f, 0.f};

    const uint4 zz = make_uint4(0, 0, 0, 0);
    for (int kc = 0; kc < 4; ++kc) {
        const uint4* xsrc = (const uint4*)(Xp + (size_t)xrow * 128 + kc * 32);
        const uint4* wsrc = (const uint4*)(Wp + (size_t)srow * 128 + kc * 32);
        uint4 xg[4], wg[4];
#pragma unroll
        for (int g = 0; g < 4; ++g) {
            xg[g] = xok ? xsrc[g] : zz;
            wg[g] = wsrc[g];
        }
        __syncthreads();
#pragma unroll
        for (int g = 0; g < 4; ++g) {
            int p = ((splane << 2) | g) ^ (srow & 7);
            *(uint4*)(Xs + srow * 64 + p * 8) = xg[g];
            *(uint4*)(Wt + srow * 64 + p * 8) = wg[g];
        }
        __syncthreads();

        short8 ah[4], al[4], bh[4], bl[4];
#pragma unroll
        for (int ri = 0; ri < 4; ++ri) {
            int row = wr + ri * 16 + frow;
            ah[ri] = *(const short8*)(Xs + row * 64 + (fk ^ (row & 7)) * 8);
            al[ri] = *(const short8*)(Xs + row * 64 + ((4 | fk) ^ (row & 7)) * 8);
        }
#pragma unroll
        for (int ci = 0; ci < 4; ++ci) {
            int col = wc + ci * 16 + frow;
            bh[ci] = *(const short8*)(Wt + col * 64 + (fk ^ (col & 7)) * 8);
            bl[ci] = *(const short8*)(Wt + col * 64 + ((4 | fk) ^ (col & 7)) * 8);
        }
#pragma unroll
        for (int ri = 0; ri < 4; ++ri)
#pragma unroll
            for (int ci = 0; ci < 4; ++ci) {
                acc[ri][ci] = MFMA16(ah[ri], bh[ci], acc[ri][ci], 0, 0, 0);
                acc[ri][ci] = MFMA16(ah[ri], bl[ci], acc[ri][ci], 0, 0, 0);
                acc[ri][ci] = MFMA16(al[ri], bh[ci], acc[ri][ci], 0, 0, 0);
            }
    }

    // epilogue: bias, stores, fused row-dots
    const float* dA = second ? dA1 : dA0;
    const float* dB = second ? nullptr : dB0;
    float dotA[4][4] = {}, dotB[4][4] = {};
#pragma unroll
    for (int ci = 0; ci < 4; ++ci) {
        int col = wc + ci * 16 + frow;
        float bcol = bias[col];
        float dAc = dA ? dA[col] : 0.f;
        float dBc = dB ? dB[col] : 0.f;
#pragma unroll
        for (int ri = 0; ri < 4; ++ri) {
            f32x4 v = acc[ri][ci];
#pragma unroll
            for (int reg = 0; reg < 4; ++reg) {
                float val = v[reg] + bcol;
                int grow = r0 + wr + ri * 16 + q4 * 4 + reg;
                if (grow < N) {
                    if (!second) Yf0[(size_t)grow * 128 + col] = val;
                    else Yb1[(size_t)grow * 128 + col] = (unsigned short)f2bf(val);
                }
                dotA[ri][reg] = fmaf(val, dAc, dotA[ri][reg]);
                dotB[ri][reg] = fmaf(val, dBc, dotB[ri][reg]);
            }
        }
    }
#pragma unroll
    for (int m = 1; m < 16; m <<= 1)
#pragma unroll
        for (int ri = 0; ri < 4; ++ri)
#pragma unroll
            for (int reg = 0; reg < 4; ++reg) {
                dotA[ri][reg] += __shfl_xor(dotA[ri][reg], m, 64);
                dotB[ri][reg] += __shfl_xor(dotB[ri][reg], m, 64);
            }
    __syncthreads();  // done with GEMM tiles; reuse LDS as dot buffer
    float* dotbuf = (float*)lds;  // [2][128][2]
    if (frow == 0) {
#pragma unroll
        for (int ri = 0; ri < 4; ++ri)
#pragma unroll
            for (int reg = 0; reg < 4; ++reg) {
                int rl = wr + ri * 16 + q4 * 4 + reg;
                dotbuf[(0 * 128 + rl) * 2 + (w & 1)] = dotA[ri][reg];
                dotbuf[(1 * 128 + rl) * 2 + (w & 1)] = dotB[ri][reg];
            }
    }
    __syncthreads();
    {
        int d = tid >> 7, rl = tid & 127;
        int grow = r0 + rl;
        float* oA = second ? oA1 : oA0;
        float* oB = second ? nullptr : oB0;
        if (grow < N) {
            float v = dotbuf[(d * 128 + rl) * 2] + dotbuf[(d * 128 + rl) * 2 + 1];
            if (d == 0) { if (oA) oA[grow] = v; }
            else        { if (oB) oB[grow] = v; }
        }
    }
}

// ---------------- aggregation: 4 nodes/block, fused w1/w2 + bf16 gather ------
__global__ __launch_bounds__(256) void k_agg(
    const float* __restrict__ xnew, const unsigned short* __restrict__ hbf,
    const float* __restrict__ x1a, const float* __restrict__ xa2a,
    const float* __restrict__ h1a, const int* __restrict__ rp,
    const int* __restrict__ ts,
    unsigned short* __restrict__ hhi, unsigned short* __restrict__ hlo, int N) {
    int u = blockIdx.x * 4 + (threadIdx.x >> 6);
    if (u >= N) return;  // wave-uniform
    int lane = threadIdx.x & 63;
    int l2 = lane << 1;
    float x1u = x1a[u];
    float w2 = expf(lrelu02(x1u + xa2a[u]));
    float2 xr = *(const float2*)(xnew + (size_t)u * 128 + l2);
    float accx = w2 * xr.x, accy = w2 * xr.y;
    float div = w2;
    int p0 = rp[u], p1 = rp[u + 1];
    for (int base = p0; base < p1; base += 64) {
        int e = base + lane;
        int tv = 0;
        float wv = 0.f;
        if (e < p1) {
            tv = ts[e];
            wv = expf(lrelu02(x1u + h1a[tv]));
        }
        int m = p1 - base; if (m > 64) m = 64;
        int j = 0;
        for (; j + 4 <= m; j += 4) {
            float w0 = __shfl(wv, j, 64),  w1 = __shfl(wv, j + 1, 64);
            float w2e = __shfl(wv, j + 2, 64), w3 = __shfl(wv, j + 3, 64);
            int t0 = __shfl(tv, j, 64),  t1 = __shfl(tv, j + 1, 64);
            int t2 = __shfl(tv, j + 2, 64), t3 = __shfl(tv, j + 3, 64);
            unsigned int h0 = *(const unsigned int*)(hbf + (size_t)t0 * 128 + l2);
            unsigned int h1 = *(const unsigned int*)(hbf + (size_t)t1 * 128 + l2);
            unsigned int h2 = *(const unsigned int*)(hbf + (size_t)t2 * 128 + l2);
            unsigned int h3 = *(const unsigned int*)(hbf + (size_t)t3 * 128 + l2);
            float2 f0 = bf2f2(h0), f1 = bf2f2(h1), f2 = bf2f2(h2), f3 = bf2f2(h3);
            accx = fmaf(w0, f0.x, accx); accy = fmaf(w0, f0.y, accy);
            accx = fmaf(w1, f1.x, accx); accy = fmaf(w1, f1.y, accy);
            accx = fmaf(w2e, f2.x, accx); accy = fmaf(w2e, f2.y, accy);
            accx = fmaf(w3, f3.x, accx); accy = fmaf(w3, f3.y, accy);
            div += (w0 + w1) + (w2e + w3);
        }
        for (; j < m; ++j) {
            float w = __shfl(wv, j, 64);
            int tt = __shfl(tv, j, 64);
            float2 f = bf2f2(*(const unsigned int*)(hbf + (size_t)tt * 128 + l2));
            accx = fmaf(w, f.x, accx); accy = fmaf(w, f.y, accy);
            div += w;
        }
    }
    float ox = accx / div, oy = accy / div;
    ox = ox > 0.f ? ox : expf(ox) - 1.f;
    oy = oy > 0.f ? oy : expf(oy) - 1.f;
    unsigned int hx = __float_as_uint(ox), hy = __float_as_uint(oy);
    *(unsigned int*)(hhi + (size_t)u * 128 + l2) = (hx >> 16) | (hy & 0xffff0000u);
    float lox = ox - __uint_as_float(hx & 0xffff0000u);
    float loy = oy - __uint_as_float(hy & 0xffff0000u);
    *(unsigned int*)(hlo + (size_t)u * 128 + l2) = f2bf(lox) | (f2bf(loy) << 16);
}

// ---------------- launch ----------------
extern "C" void kernel_launch(void* const* d_in, const int* in_sizes, int n_in,
                              void* d_out, int out_size, void* d_ws, size_t ws_size,
                              hipStream_t stream) {
    const float* x_in = (const float*)d_in[0];
    const int*   s    = (const int*)d_in[1];
    const int*   t    = (const int*)d_in[2];
    const float* fc1W = (const float*)d_in[3];
    const float* fc1b = (const float*)d_in[4];
    const float* fcsW = (const float*)d_in[5];
    const float* fcsb = (const float*)d_in[6];
    const float* a1   = (const float*)d_in[7];
    const float* a2   = (const float*)d_in[8];
    const float* fc2W = (const float*)d_in[9];
    const float* fc2b = (const float*)d_in[10];

    const int N = in_sizes[0] / 256;  // 50000
    const int E = in_sizes[1];        // 800000
    const int G = (N + 255) / 256;
    const int NB = (N + 127) / 128;   // 391

    char* ws = (char*)d_ws;
    size_t off = 0;
    auto alloc = [&](size_t bytes) -> void* {
        void* p = ws + off;
        off += (bytes + 255) & ~(size_t)255;
        return p;
    };
    unsigned short* xbuf_hi = (unsigned short*)alloc((size_t)N * 128 * 2);
    unsigned short* xbuf_lo = (unsigned short*)alloc((size_t)N * 128 * 2);
    unsigned short* h_hi    = (unsigned short*)alloc((size_t)N * 128 * 2);
    unsigned short* h_lo    = (unsigned short*)alloc((size_t)N * 128 * 2);
    float* xnew = (float*)alloc((size_t)N * 128 * 4);
    unsigned short* hbf = (unsigned short*)alloc((size_t)N * 128 * 2);
    unsigned short* Whi = (unsigned short*)alloc((size_t)10 * 128 * 128 * 2);
    unsigned short* Wlo = (unsigned short*)alloc((size_t)10 * 128 * 128 * 2);
    float* x1a  = (float*)alloc((size_t)N * 4);
    float* xa2a = (float*)alloc((size_t)N * 4);
    float* h1a  = (float*)alloc((size_t)N * 4);
    int* row_ptr  = (int*)alloc((size_t)(N + 1) * 4);
    int* cnt      = (int*)alloc((size_t)N * 4);
    int* bsums    = (int*)alloc((size_t)256 * 4);
    int* t_sorted = (int*)alloc((size_t)E * 4);

    // CSR build
    hipMemsetAsync(cnt, 0, (size_t)N * 4, stream);
    k_count<<<(E + 255) / 256, 256, 0, stream>>>(s, cnt, E);
    k_scan1<<<G, 256, 0, stream>>>(cnt, bsums, N);
    k_scan2<<<1, 256, 0, stream>>>(bsums, G);
    k_scan3<<<G, 256, 0, stream>>>(cnt, bsums, row_ptr, N);
    hipMemsetAsync(cnt, 0, (size_t)N * 4, stream);
    k_scatter<<<(E + 255) / 256, 256, 0, stream>>>(s, t, row_ptr, cnt, t_sorted, E);

    // W splits for the 10 hop weights
    k_wsplit<<<(10 * 128 * 128 + 255) / 256, 256, 0, stream>>>(fcsW, Whi, Wlo, 10 * 128 * 128);

    // fc1 + relu -> split planes
    k_mm<<<NB, 256, 0, stream>>>(x_in, nullptr, nullptr, fc1W, fc1b,
                                 nullptr, xbuf_hi, xbuf_lo, N, 256, 128, 128, 1);

    // hops
    const unsigned short* hs_hi = xbuf_hi;
    const unsigned short* hs_lo = xbuf_lo;
    for (int i = 0; i < 10; ++i) {
        const unsigned short* Wh = Whi + (size_t)i * 128 * 128;
        const unsigned short* Wl = Wlo + (size_t)i * 128 * 128;
        const float* b   = fcsb + (size_t)i * 128;
        const float* a1i = a1 + (size_t)i * 128;
        const float* a2i = a2 + (size_t)i * 128;
        k_mm_bf<<<2 * NB, 256, 0, stream>>>(xbuf_hi, xbuf_lo, NB, hs_hi, hs_lo,
                                            Wh, Wl, b, xnew, hbf, N,
                                            a1i, x1a, a2i, xa2a, a2i, h1a);
        k_agg<<<(N + 3) / 4, 256, 0, stream>>>(xnew, hbf, x1a, xa2a, h1a,
                                               row_ptr, t_sorted, h_hi, h_lo, N);
        hs_hi = h_hi; hs_lo = h_lo;
    }

    // fc2 from reconstructed h planes
    k_mm<<<NB, 256, 0, stream>>>(nullptr, h_hi, h_lo, fc2W, fc2b,
                                 (float*)d_out, nullptr, nullptr, N, 128, 64, 64, 0);
}

// Round 5
// 1217.448 us; speedup vs baseline: 1.1966x; 1.0423x over previous
//
#include <hip/hip_runtime.h>
#include <math.h>

// ---------------------------------------------------------------------------
// GTAN2 R5: all GEMMs on MFMA. k_mmfc<1> = fc1 (fp32 in, split during LDS
// staging, relu+split-plane out). k_mmfc<2> = fc2 (plane in, fp32 out, 64
// cols). Hop k_mm_bf unchanged (R4-proven). k_agg: LDS-staged (t,w) pairs +
// 8-deep gather groups (no bpermute chains, no serial tail).
// ---------------------------------------------------------------------------

typedef __attribute__((ext_vector_type(8))) short short8;
typedef __attribute__((ext_vector_type(4))) float f32x4;
#define MFMA16 __builtin_amdgcn_mfma_f32_16x16x32_bf16

__device__ __forceinline__ float lrelu02(float v) { return v > 0.f ? v : 0.2f * v; }

__device__ __forceinline__ float2 bf2f2(unsigned int v) {
    return make_float2(__uint_as_float(v << 16), __uint_as_float(v & 0xffff0000u));
}
__device__ __forceinline__ unsigned int f2bf(float f) {  // RNE bf16
    unsigned int u = __float_as_uint(f);
    u += 0x7fffu + ((u >> 16) & 1u);
    return u >> 16;
}
__device__ __forceinline__ float hi_part(float f) {  // truncate mantissa to bf16
    return __uint_as_float(__float_as_uint(f) & 0xffff0000u);
}
__device__ __forceinline__ uint4 pack_hi(const float4& a, const float4& b) {
    uint4 r;
    r.x = (__float_as_uint(a.x) >> 16) | (__float_as_uint(a.y) & 0xffff0000u);
    r.y = (__float_as_uint(a.z) >> 16) | (__float_as_uint(a.w) & 0xffff0000u);
    r.z = (__float_as_uint(b.x) >> 16) | (__float_as_uint(b.y) & 0xffff0000u);
    r.w = (__float_as_uint(b.z) >> 16) | (__float_as_uint(b.w) & 0xffff0000u);
    return r;
}
__device__ __forceinline__ uint4 pack_lo(const float4& a, const float4& b) {
    uint4 r;
    r.x = f2bf(a.x - hi_part(a.x)) | (f2bf(a.y - hi_part(a.y)) << 16);
    r.y = f2bf(a.z - hi_part(a.z)) | (f2bf(a.w - hi_part(a.w)) << 16);
    r.z = f2bf(b.x - hi_part(b.x)) | (f2bf(b.y - hi_part(b.y)) << 16);
    r.w = f2bf(b.z - hi_part(b.z)) | (f2bf(b.w - hi_part(b.w)) << 16);
    return r;
}

// ---------------- CSR build ----------------
__global__ __launch_bounds__(256) void k_count(const int* __restrict__ s, int* __restrict__ cnt, int E) {
    int e = blockIdx.x * 256 + threadIdx.x;
    if (e < E) atomicAdd(&cnt[s[e]], 1);
}

__global__ __launch_bounds__(256) void k_scan1(const int* __restrict__ cnt, int* __restrict__ bs, int N) {
    __shared__ int sh[256];
    int idx = blockIdx.x * 256 + threadIdx.x;
    sh[threadIdx.x] = (idx < N) ? cnt[idx] : 0;
    __syncthreads();
#pragma unroll
    for (int off = 128; off; off >>= 1) {
        if (threadIdx.x < off) sh[threadIdx.x] += sh[threadIdx.x + off];
        __syncthreads();
    }
    if (threadIdx.x == 0) bs[blockIdx.x] = sh[0];
}

__global__ __launch_bounds__(256) void k_scan2(int* __restrict__ bs, int G) {
    __shared__ int sh[256];
    int t = threadIdx.x;
    int v = (t < G) ? bs[t] : 0;
    sh[t] = v;
    __syncthreads();
    int val = v;
#pragma unroll
    for (int off = 1; off < 256; off <<= 1) {
        int o = (t >= off) ? sh[t - off] : 0;
        __syncthreads();
        val += o; sh[t] = val;
        __syncthreads();
    }
    if (t < G) bs[t] = val - v;  // exclusive
}

__global__ __launch_bounds__(256) void k_scan3(const int* __restrict__ cnt, const int* __restrict__ bs,
                                               int* __restrict__ rp, int N) {
    __shared__ int sh[256];
    int t = threadIdx.x;
    int idx = blockIdx.x * 256 + t;
    int v = (idx < N) ? cnt[idx] : 0;
    sh[t] = v;
    __syncthreads();
    int val = v;
#pragma unroll
    for (int off = 1; off < 256; off <<= 1) {
        int o = (t >= off) ? sh[t - off] : 0;
        __syncthreads();
        val += o; sh[t] = val;
        __syncthreads();
    }
    if (idx <= N) rp[idx] = val - v + bs[blockIdx.x];
}

__global__ __launch_bounds__(256) void k_scatter(const int* __restrict__ s, const int* __restrict__ t,
                                                 const int* __restrict__ rp, int* __restrict__ cursor,
                                                 int* __restrict__ t_sorted, int E) {
    int e = blockIdx.x * 256 + threadIdx.x;
    if (e < E) {
        int u = s[e];
        int pos = atomicAdd(&cursor[u], 1);
        t_sorted[rp[u] + pos] = t[e];
    }
}

// ---------------- W split for hop weights ----------------
__global__ __launch_bounds__(256) void k_wsplit(const float* __restrict__ W,
                                                unsigned short* __restrict__ Whi,
                                                unsigned short* __restrict__ Wlo, int total) {
    int i = blockIdx.x * 256 + threadIdx.x;
    if (i < total) {
        float f = W[i];
        unsigned int u = __float_as_uint(f);
        Whi[i] = (unsigned short)(u >> 16);
        Wlo[i] = (unsigned short)f2bf(f - __uint_as_float(u & 0xffff0000u));
    }
}

// ---------------- fc1/fc2 MFMA GEMM (split-bf16 3-term) ----------------
// MODE 1 = fc1: fp32 X [N,256] & fp32 W [128,256], relu, split-plane out.
// MODE 2 = fc2: plane X [N,128] & fp32 W [64,128], fp32 out [N,64].
template <int MODE>
__global__ __launch_bounds__(256) void k_mmfc(
    const float* __restrict__ Xf,
    const unsigned short* __restrict__ Xhi, const unsigned short* __restrict__ Xlo,
    const float* __restrict__ Wf, const float* __restrict__ bias,
    float* __restrict__ Yf, unsigned short* __restrict__ Yhi, unsigned short* __restrict__ Ylo,
    int N) {
    constexpr int K = (MODE == 1) ? 256 : 128;
    constexpr int NCOLS = (MODE == 1) ? 128 : 64;
    __shared__ unsigned short lds[2 * 128 * 64];  // 32 KB
    unsigned short* Xs = lds;
    unsigned short* Wt = lds + 128 * 64;

    const int tid = threadIdx.x;
    const int r0 = blockIdx.x * 128;
    const int srow = tid & 127;
    const int sp = tid >> 7;  // MODE1: khalf; MODE2: X-plane / W-khalf
    const int xrow = r0 + srow;
    const bool xok = xrow < N;
    const bool wok = srow < NCOLS;

    const int lane = tid & 63;
    const int w = tid >> 6;
    const int wr = (w >> 1) * 64, wc = (w & 1) * 64;
    const int frow = lane & 15;
    const int fk = lane >> 4;
    const int q4 = lane >> 4;

    f32x4 acc[4][4];
#pragma unroll
    for (int i = 0; i < 4; ++i)
#pragma unroll
        for (int j = 0; j < 4; ++j) acc[i][j] = (f32x4){0.f, 0.f, 0.f, 0.f};

    const float4 z4 = make_float4(0.f, 0.f, 0.f, 0.f);
    const uint4 zz = make_uint4(0, 0, 0, 0);

    for (int kc = 0; kc < K / 32; ++kc) {
        if constexpr (MODE == 1) {
            // both X and W are fp32: split during staging (sp = khalf)
            const float* xp = Xf + (size_t)xrow * K + kc * 32 + sp * 16;
            const float* wp = Wf + (size_t)srow * K + kc * 32 + sp * 16;
            float4 xv[4], wv[4];
#pragma unroll
            for (int q = 0; q < 4; ++q) {
                xv[q] = xok ? *(const float4*)(xp + q * 4) : z4;
                wv[q] = wok ? *(const float4*)(wp + q * 4) : z4;
            }
            __syncthreads();
#pragma unroll
            for (int j = 0; j < 2; ++j) {
                int g = sp * 2 + j;
                *(uint4*)(Xs + srow * 64 + ((g) ^ (srow & 7)) * 8)     = pack_hi(xv[2 * j], xv[2 * j + 1]);
                *(uint4*)(Xs + srow * 64 + ((4 | g) ^ (srow & 7)) * 8) = pack_lo(xv[2 * j], xv[2 * j + 1]);
                *(uint4*)(Wt + srow * 64 + ((g) ^ (srow & 7)) * 8)     = pack_hi(wv[2 * j], wv[2 * j + 1]);
                *(uint4*)(Wt + srow * 64 + ((4 | g) ^ (srow & 7)) * 8) = pack_lo(wv[2 * j], wv[2 * j + 1]);
            }
            __syncthreads();
        } else {
            // X from planes (sp = plane), W fp32 split (sp = khalf)
            const unsigned short* xp = (sp ? Xlo : Xhi) + (size_t)xrow * K + kc * 32;
            const float* wp = Wf + (size_t)srow * K + kc * 32 + sp * 16;
            uint4 xg[4];
            float4 wv[4];
#pragma unroll
            for (int g = 0; g < 4; ++g) xg[g] = xok ? ((const uint4*)xp)[g] : zz;
#pragma unroll
            for (int q = 0; q < 4; ++q) wv[q] = wok ? *(const float4*)(wp + q * 4) : z4;
            __syncthreads();
#pragma unroll
            for (int g = 0; g < 4; ++g) {
                int p = ((sp << 2) | g) ^ (srow & 7);
                *(uint4*)(Xs + srow * 64 + p * 8) = xg[g];
            }
#pragma unroll
            for (int j = 0; j < 2; ++j) {
                int g = sp * 2 + j;
                *(uint4*)(Wt + srow * 64 + ((g) ^ (srow & 7)) * 8)     = pack_hi(wv[2 * j], wv[2 * j + 1]);
                *(uint4*)(Wt + srow * 64 + ((4 | g) ^ (srow & 7)) * 8) = pack_lo(wv[2 * j], wv[2 * j + 1]);
            }
            __syncthreads();
        }

        short8 ah[4], al[4], bh[4], bl[4];
#pragma unroll
        for (int ri = 0; ri < 4; ++ri) {
            int row = wr + ri * 16 + frow;
            ah[ri] = *(const short8*)(Xs + row * 64 + ((fk) ^ (row & 7)) * 8);
            al[ri] = *(const short8*)(Xs + row * 64 + ((4 | fk) ^ (row & 7)) * 8);
        }
#pragma unroll
        for (int ci = 0; ci < 4; ++ci) {
            int col = wc + ci * 16 + frow;
            bh[ci] = *(const short8*)(Wt + col * 64 + ((fk) ^ (col & 7)) * 8);
            bl[ci] = *(const short8*)(Wt + col * 64 + ((4 | fk) ^ (col & 7)) * 8);
        }
#pragma unroll
        for (int ri = 0; ri < 4; ++ri)
#pragma unroll
            for (int ci = 0; ci < 4; ++ci) {
                acc[ri][ci] = MFMA16(ah[ri], bh[ci], acc[ri][ci], 0, 0, 0);
                acc[ri][ci] = MFMA16(ah[ri], bl[ci], acc[ri][ci], 0, 0, 0);
                acc[ri][ci] = MFMA16(al[ri], bh[ci], acc[ri][ci], 0, 0, 0);
            }
    }

#pragma unroll
    for (int ci = 0; ci < 4; ++ci) {
        int col = wc + ci * 16 + frow;
        float bcol = (col < NCOLS) ? bias[col] : 0.f;
#pragma unroll
        for (int ri = 0; ri < 4; ++ri) {
            f32x4 v = acc[ri][ci];
#pragma unroll
            for (int reg = 0; reg < 4; ++reg) {
                int grow = r0 + wr + ri * 16 + q4 * 4 + reg;
                float val = v[reg] + bcol;
                if (grow < N && col < NCOLS) {
                    if constexpr (MODE == 1) {
                        val = fmaxf(val, 0.f);
                        Yhi[(size_t)grow * 128 + col] = (unsigned short)(__float_as_uint(val) >> 16);
                        Ylo[(size_t)grow * 128 + col] = (unsigned short)f2bf(val - hi_part(val));
                    } else {
                        Yf[(size_t)grow * 64 + col] = val;
                    }
                }
            }
        }
    }
}

// ---------------- hop GEMM: split-bf16 MFMA, dual-source (R4-proven) --------
__global__ __launch_bounds__(256) void k_mm_bf(
    const unsigned short* __restrict__ Xhi0, const unsigned short* __restrict__ Xlo0, int nblk0,
    const unsigned short* __restrict__ Xhi1, const unsigned short* __restrict__ Xlo1,
    const unsigned short* __restrict__ Whi, const unsigned short* __restrict__ Wlo,
    const float* __restrict__ bias,
    float* __restrict__ Yf0, unsigned short* __restrict__ Yb1, int N,
    const float* __restrict__ dA0, float* __restrict__ oA0,
    const float* __restrict__ dB0, float* __restrict__ oB0,
    const float* __restrict__ dA1, float* __restrict__ oA1) {
    __shared__ unsigned short lds[2 * 128 * 64];  // 32 KB
    unsigned short* Xs = lds;
    unsigned short* Wt = lds + 128 * 64;

    const int tid = threadIdx.x;
    const bool second = (int)blockIdx.x >= nblk0;
    const int bx = second ? (int)blockIdx.x - nblk0 : (int)blockIdx.x;
    const int r0 = bx * 128;
    const int srow = tid & 127;
    const int splane = tid >> 7;
    const unsigned short* Xp = second ? (splane ? Xlo1 : Xhi1) : (splane ? Xlo0 : Xhi0);
    const unsigned short* Wp = splane ? Wlo : Whi;
    const int xrow = r0 + srow;
    const bool xok = xrow < N;

    const int lane = tid & 63;
    const int w = tid >> 6;
    const int wr = (w >> 1) * 64, wc = (w & 1) * 64;
    const int frow = lane & 15;
    const int fk = lane >> 4;
    const int q4 = lane >> 4;

    f32x4 acc[4][4];
#pragma unroll
    for (int i = 0; i < 4; ++i)
#pragma unroll
        for (int j = 0; j < 4; ++j) acc[i][j] = (f32x4){0.f, 0.f, 0.f, 0.f};

    const uint4 zz = make_uint4(0, 0, 0, 0);
    for (int kc = 0; kc < 4; ++kc) {
        const uint4* xsrc = (const uint4*)(Xp + (size_t)xrow * 128 + kc * 32);
        const uint4* wsrc = (const uint4*)(Wp + (size_t)srow * 128 + kc * 32);
        uint4 xg[4], wg[4];
#pragma unroll
        for (int g = 0; g < 4; ++g) {
            xg[g] = xok ? xsrc[g] : zz;
            wg[g] = wsrc[g];
        }
        __syncthreads();
#pragma unroll
        for (int g = 0; g < 4; ++g) {
            int p = ((splane << 2) | g) ^ (srow & 7);
            *(uint4*)(Xs + srow * 64 + p * 8) = xg[g];
            *(uint4*)(Wt + srow * 64 + p * 8) = wg[g];
        }
        __syncthreads();

        short8 ah[4], al[4], bh[4], bl[4];
#pragma unroll
        for (int ri = 0; ri < 4; ++ri) {
            int row = wr + ri * 16 + frow;
            ah[ri] = *(const short8*)(Xs + row * 64 + (fk ^ (row & 7)) * 8);
            al[ri] = *(const short8*)(Xs + row * 64 + ((4 | fk) ^ (row & 7)) * 8);
        }
#pragma unroll
        for (int ci = 0; ci < 4; ++ci) {
            int col = wc + ci * 16 + frow;
            bh[ci] = *(const short8*)(Wt + col * 64 + (fk ^ (col & 7)) * 8);
            bl[ci] = *(const short8*)(Wt + col * 64 + ((4 | fk) ^ (col & 7)) * 8);
        }
#pragma unroll
        for (int ri = 0; ri < 4; ++ri)
#pragma unroll
            for (int ci = 0; ci < 4; ++ci) {
                acc[ri][ci] = MFMA16(ah[ri], bh[ci], acc[ri][ci], 0, 0, 0);
                acc[ri][ci] = MFMA16(ah[ri], bl[ci], acc[ri][ci], 0, 0, 0);
                acc[ri][ci] = MFMA16(al[ri], bh[ci], acc[ri][ci], 0, 0, 0);
            }
    }

    const float* dA = second ? dA1 : dA0;
    const float* dB = second ? nullptr : dB0;
    float dotA[4][4] = {}, dotB[4][4] = {};
#pragma unroll
    for (int ci = 0; ci < 4; ++ci) {
        int col = wc + ci * 16 + frow;
        float bcol = bias[col];
        float dAc = dA ? dA[col] : 0.f;
        float dBc = dB ? dB[col] : 0.f;
#pragma unroll
        for (int ri = 0; ri < 4; ++ri) {
            f32x4 v = acc[ri][ci];
#pragma unroll
            for (int reg = 0; reg < 4; ++reg) {
                float val = v[reg] + bcol;
                int grow = r0 + wr + ri * 16 + q4 * 4 + reg;
                if (grow < N) {
                    if (!second) Yf0[(size_t)grow * 128 + col] = val;
                    else Yb1[(size_t)grow * 128 + col] = (unsigned short)f2bf(val);
                }
                dotA[ri][reg] = fmaf(val, dAc, dotA[ri][reg]);
                dotB[ri][reg] = fmaf(val, dBc, dotB[ri][reg]);
            }
        }
    }
#pragma unroll
    for (int m = 1; m < 16; m <<= 1)
#pragma unroll
        for (int ri = 0; ri < 4; ++ri)
#pragma unroll
            for (int reg = 0; reg < 4; ++reg) {
                dotA[ri][reg] += __shfl_xor(dotA[ri][reg], m, 64);
                dotB[ri][reg] += __shfl_xor(dotB[ri][reg], m, 64);
            }
    __syncthreads();
    float* dotbuf = (float*)lds;  // [2][128][2]
    if (frow == 0) {
#pragma unroll
        for (int ri = 0; ri < 4; ++ri)
#pragma unroll
            for (int reg = 0; reg < 4; ++reg) {
                int rl = wr + ri * 16 + q4 * 4 + reg;
                dotbuf[(0 * 128 + rl) * 2 + (w & 1)] = dotA[ri][reg];
                dotbuf[(1 * 128 + rl) * 2 + (w & 1)] = dotB[ri][reg];
            }
    }
    __syncthreads();
    {
        int d = tid >> 7, rl = tid & 127;
        int grow = r0 + rl;
        float* oA = second ? oA1 : oA0;
        float* oB = second ? nullptr : oB0;
        if (grow < N) {
            float v = dotbuf[(d * 128 + rl) * 2] + dotbuf[(d * 128 + rl) * 2 + 1];
            if (d == 0) { if (oA) oA[grow] = v; }
            else        { if (oB) oB[grow] = v; }
        }
    }
}

// ---------------- aggregation: LDS-staged (t,w), 8-deep gather groups --------
__global__ __launch_bounds__(256) void k_agg(
    const float* __restrict__ xnew, const unsigned short* __restrict__ hbf,
    const float* __restrict__ x1a, const float* __restrict__ xa2a,
    const float* __restrict__ h1a, const int* __restrict__ rp,
    const int* __restrict__ ts,
    unsigned short* __restrict__ hhi, unsigned short* __restrict__ hlo, int N) {
    __shared__ uint2 ew[4][64];
    const int wid = threadIdx.x >> 6;
    const int lane = threadIdx.x & 63;
    const int u = blockIdx.x * 4 + wid;
    if (u >= N) return;  // no barriers below; per-wave LDS slice only
    const int l2 = lane << 1;
    float x1u = x1a[u];
    float w2 = expf(lrelu02(x1u + xa2a[u]));
    float2 xr = *(const float2*)(xnew + (size_t)u * 128 + l2);
    float accx = w2 * xr.x, accy = w2 * xr.y;
    float div = w2;
    int p0 = rp[u], p1 = rp[u + 1];
    for (int base = p0; base < p1; base += 64) {
        int e = base + lane;
        uint2 pk = make_uint2(0u, 0u);  // t=0, w=0 pad: zero contribution
        if (e < p1) {
            int tv = ts[e];
            pk.x = (unsigned int)tv;
            pk.y = __float_as_uint(expf(lrelu02(x1u + h1a[tv])));
        }
        ew[wid][lane] = pk;
        int m = p1 - base; if (m > 64) m = 64;
        int m8 = (m + 7) & ~7;
        for (int j = 0; j < m8; j += 8) {
            uint2 q[8];
#pragma unroll
            for (int k = 0; k < 8; ++k) q[k] = ew[wid][j + k];
            unsigned int hv[8];
#pragma unroll
            for (int k = 0; k < 8; ++k)
                hv[k] = *(const unsigned int*)(hbf + (size_t)q[k].x * 128 + l2);
#pragma unroll
            for (int k = 0; k < 8; ++k) {
                float ww = __uint_as_float(q[k].y);
                float2 f = bf2f2(hv[k]);
                accx = fmaf(ww, f.x, accx);
                accy = fmaf(ww, f.y, accy);
                div += ww;
            }
        }
    }
    float ox = accx / div, oy = accy / div;
    ox = ox > 0.f ? ox : expf(ox) - 1.f;
    oy = oy > 0.f ? oy : expf(oy) - 1.f;
    unsigned int hx = __float_as_uint(ox), hy = __float_as_uint(oy);
    *(unsigned int*)(hhi + (size_t)u * 128 + l2) = (hx >> 16) | (hy & 0xffff0000u);
    float lox = ox - __uint_as_float(hx & 0xffff0000u);
    float loy = oy - __uint_as_float(hy & 0xffff0000u);
    *(unsigned int*)(hlo + (size_t)u * 128 + l2) = f2bf(lox) | (f2bf(loy) << 16);
}

// ---------------- launch ----------------
extern "C" void kernel_launch(void* const* d_in, const int* in_sizes, int n_in,
                              void* d_out, int out_size, void* d_ws, size_t ws_size,
                              hipStream_t stream) {
    const float* x_in = (const float*)d_in[0];
    const int*   s    = (const int*)d_in[1];
    const int*   t    = (const int*)d_in[2];
    const float* fc1W = (const float*)d_in[3];
    const float* fc1b = (const float*)d_in[4];
    const float* fcsW = (const float*)d_in[5];
    const float* fcsb = (const float*)d_in[6];
    const float* a1   = (const float*)d_in[7];
    const float* a2   = (const float*)d_in[8];
    const float* fc2W = (const float*)d_in[9];
    const float* fc2b = (const float*)d_in[10];

    const int N = in_sizes[0] / 256;  // 50000
    const int E = in_sizes[1];        // 800000
    const int G = (N + 255) / 256;
    const int NB = (N + 127) / 128;   // 391

    char* ws = (char*)d_ws;
    size_t off = 0;
    auto alloc = [&](size_t bytes) -> void* {
        void* p = ws + off;
        off += (bytes + 255) & ~(size_t)255;
        return p;
    };
    unsigned short* xbuf_hi = (unsigned short*)alloc((size_t)N * 128 * 2);
    unsigned short* xbuf_lo = (unsigned short*)alloc((size_t)N * 128 * 2);
    unsigned short* h_hi    = (unsigned short*)alloc((size_t)N * 128 * 2);
    unsigned short* h_lo    = (unsigned short*)alloc((size_t)N * 128 * 2);
    float* xnew = (float*)alloc((size_t)N * 128 * 4);
    unsigned short* hbf = (unsigned short*)alloc((size_t)N * 128 * 2);
    unsigned short* Whi = (unsigned short*)alloc((size_t)10 * 128 * 128 * 2);
    unsigned short* Wlo = (unsigned short*)alloc((size_t)10 * 128 * 128 * 2);
    float* x1a  = (float*)alloc((size_t)N * 4);
    float* xa2a = (float*)alloc((size_t)N * 4);
    float* h1a  = (float*)alloc((size_t)N * 4);
    int* row_ptr  = (int*)alloc((size_t)(N + 1) * 4);
    int* cnt      = (int*)alloc((size_t)N * 4);
    int* bsums    = (int*)alloc((size_t)256 * 4);
    int* t_sorted = (int*)alloc((size_t)E * 4);

    // CSR build
    hipMemsetAsync(cnt, 0, (size_t)N * 4, stream);
    k_count<<<(E + 255) / 256, 256, 0, stream>>>(s, cnt, E);
    k_scan1<<<G, 256, 0, stream>>>(cnt, bsums, N);
    k_scan2<<<1, 256, 0, stream>>>(bsums, G);
    k_scan3<<<G, 256, 0, stream>>>(cnt, bsums, row_ptr, N);
    hipMemsetAsync(cnt, 0, (size_t)N * 4, stream);
    k_scatter<<<(E + 255) / 256, 256, 0, stream>>>(s, t, row_ptr, cnt, t_sorted, E);

    // W splits for hop weights
    k_wsplit<<<(10 * 128 * 128 + 255) / 256, 256, 0, stream>>>(fcsW, Whi, Wlo, 10 * 128 * 128);

    // fc1 + relu -> split planes (MFMA)
    k_mmfc<1><<<NB, 256, 0, stream>>>(x_in, nullptr, nullptr, fc1W, fc1b,
                                      nullptr, xbuf_hi, xbuf_lo, N);

    // hops
    const unsigned short* hs_hi = xbuf_hi;
    const unsigned short* hs_lo = xbuf_lo;
    for (int i = 0; i < 10; ++i) {
        const unsigned short* Wh = Whi + (size_t)i * 128 * 128;
        const unsigned short* Wl = Wlo + (size_t)i * 128 * 128;
        const float* b   = fcsb + (size_t)i * 128;
        const float* a1i = a1 + (size_t)i * 128;
        const float* a2i = a2 + (size_t)i * 128;
        k_mm_bf<<<2 * NB, 256, 0, stream>>>(xbuf_hi, xbuf_lo, NB, hs_hi, hs_lo,
                                            Wh, Wl, b, xnew, hbf, N,
                                            a1i, x1a, a2i, xa2a, a2i, h1a);
        k_agg<<<(N + 3) / 4, 256, 0, stream>>>(xnew, hbf, x1a, xa2a, h1a,
                                               row_ptr, t_sorted, h_hi, h_lo, N);
        hs_hi = h_hi; hs_lo = h_lo;
    }

    // fc2 (MFMA, planes in, fp32 out)
    k_mmfc<2><<<NB, 256, 0, stream>>>(nullptr, h_hi, h_lo, fc2W, fc2b,
                                      (float*)d_out, nullptr, nullptr, N);
}

// Round 6
// 1138.687 us; speedup vs baseline: 1.2794x; 1.0692x over previous
//
#include <hip/hip_runtime.h>
#include <math.h>

// ---------------------------------------------------------------------------
// GTAN2 R6: k_mm_bf epilogue rewritten — outputs staged as bf16 in LDS
// (dword-XOR swizzle by row), cooperative full-line uint4 stores. xnew is now
// a single bf16 plane (k_agg self-term only; its dot is fp32 in epilogue).
// Everything else identical to R5.
// ---------------------------------------------------------------------------

typedef __attribute__((ext_vector_type(8))) short short8;
typedef __attribute__((ext_vector_type(4))) float f32x4;
#define MFMA16 __builtin_amdgcn_mfma_f32_16x16x32_bf16

__device__ __forceinline__ float lrelu02(float v) { return v > 0.f ? v : 0.2f * v; }

__device__ __forceinline__ float2 bf2f2(unsigned int v) {
    return make_float2(__uint_as_float(v << 16), __uint_as_float(v & 0xffff0000u));
}
__device__ __forceinline__ unsigned int f2bf(float f) {  // RNE bf16
    unsigned int u = __float_as_uint(f);
    u += 0x7fffu + ((u >> 16) & 1u);
    return u >> 16;
}
__device__ __forceinline__ float hi_part(float f) {  // truncate mantissa to bf16
    return __uint_as_float(__float_as_uint(f) & 0xffff0000u);
}
__device__ __forceinline__ uint4 pack_hi(const float4& a, const float4& b) {
    uint4 r;
    r.x = (__float_as_uint(a.x) >> 16) | (__float_as_uint(a.y) & 0xffff0000u);
    r.y = (__float_as_uint(a.z) >> 16) | (__float_as_uint(a.w) & 0xffff0000u);
    r.z = (__float_as_uint(b.x) >> 16) | (__float_as_uint(b.y) & 0xffff0000u);
    r.w = (__float_as_uint(b.z) >> 16) | (__float_as_uint(b.w) & 0xffff0000u);
    return r;
}
__device__ __forceinline__ uint4 pack_lo(const float4& a, const float4& b) {
    uint4 r;
    r.x = f2bf(a.x - hi_part(a.x)) | (f2bf(a.y - hi_part(a.y)) << 16);
    r.y = f2bf(a.z - hi_part(a.z)) | (f2bf(a.w - hi_part(a.w)) << 16);
    r.z = f2bf(b.x - hi_part(b.x)) | (f2bf(b.y - hi_part(b.y)) << 16);
    r.w = f2bf(b.z - hi_part(b.z)) | (f2bf(b.w - hi_part(b.w)) << 16);
    return r;
}

// ---------------- CSR build ----------------
__global__ __launch_bounds__(256) void k_count(const int* __restrict__ s, int* __restrict__ cnt, int E) {
    int e = blockIdx.x * 256 + threadIdx.x;
    if (e < E) atomicAdd(&cnt[s[e]], 1);
}

__global__ __launch_bounds__(256) void k_scan1(const int* __restrict__ cnt, int* __restrict__ bs, int N) {
    __shared__ int sh[256];
    int idx = blockIdx.x * 256 + threadIdx.x;
    sh[threadIdx.x] = (idx < N) ? cnt[idx] : 0;
    __syncthreads();
#pragma unroll
    for (int off = 128; off; off >>= 1) {
        if (threadIdx.x < off) sh[threadIdx.x] += sh[threadIdx.x + off];
        __syncthreads();
    }
    if (threadIdx.x == 0) bs[blockIdx.x] = sh[0];
}

__global__ __launch_bounds__(256) void k_scan2(int* __restrict__ bs, int G) {
    __shared__ int sh[256];
    int t = threadIdx.x;
    int v = (t < G) ? bs[t] : 0;
    sh[t] = v;
    __syncthreads();
    int val = v;
#pragma unroll
    for (int off = 1; off < 256; off <<= 1) {
        int o = (t >= off) ? sh[t - off] : 0;
        __syncthreads();
        val += o; sh[t] = val;
        __syncthreads();
    }
    if (t < G) bs[t] = val - v;  // exclusive
}

__global__ __launch_bounds__(256) void k_scan3(const int* __restrict__ cnt, const int* __restrict__ bs,
                                               int* __restrict__ rp, int N) {
    __shared__ int sh[256];
    int t = threadIdx.x;
    int idx = blockIdx.x * 256 + t;
    int v = (idx < N) ? cnt[idx] : 0;
    sh[t] = v;
    __syncthreads();
    int val = v;
#pragma unroll
    for (int off = 1; off < 256; off <<= 1) {
        int o = (t >= off) ? sh[t - off] : 0;
        __syncthreads();
        val += o; sh[t] = val;
        __syncthreads();
    }
    if (idx <= N) rp[idx] = val - v + bs[blockIdx.x];
}

__global__ __launch_bounds__(256) void k_scatter(const int* __restrict__ s, const int* __restrict__ t,
                                                 const int* __restrict__ rp, int* __restrict__ cursor,
                                                 int* __restrict__ t_sorted, int E) {
    int e = blockIdx.x * 256 + threadIdx.x;
    if (e < E) {
        int u = s[e];
        int pos = atomicAdd(&cursor[u], 1);
        t_sorted[rp[u] + pos] = t[e];
    }
}

// ---------------- W split for hop weights ----------------
__global__ __launch_bounds__(256) void k_wsplit(const float* __restrict__ W,
                                                unsigned short* __restrict__ Whi,
                                                unsigned short* __restrict__ Wlo, int total) {
    int i = blockIdx.x * 256 + threadIdx.x;
    if (i < total) {
        float f = W[i];
        unsigned int u = __float_as_uint(f);
        Whi[i] = (unsigned short)(u >> 16);
        Wlo[i] = (unsigned short)f2bf(f - __uint_as_float(u & 0xffff0000u));
    }
}

// ---------------- fc1/fc2 MFMA GEMM (split-bf16 3-term) ----------------
// MODE 1 = fc1: fp32 X [N,256] & fp32 W [128,256], relu, split-plane out.
// MODE 2 = fc2: plane X [N,128] & fp32 W [64,128], fp32 out [N,64].
template <int MODE>
__global__ __launch_bounds__(256) void k_mmfc(
    const float* __restrict__ Xf,
    const unsigned short* __restrict__ Xhi, const unsigned short* __restrict__ Xlo,
    const float* __restrict__ Wf, const float* __restrict__ bias,
    float* __restrict__ Yf, unsigned short* __restrict__ Yhi, unsigned short* __restrict__ Ylo,
    int N) {
    constexpr int K = (MODE == 1) ? 256 : 128;
    constexpr int NCOLS = (MODE == 1) ? 128 : 64;
    __shared__ unsigned short lds[2 * 128 * 64];  // 32 KB
    unsigned short* Xs = lds;
    unsigned short* Wt = lds + 128 * 64;

    const int tid = threadIdx.x;
    const int r0 = blockIdx.x * 128;
    const int srow = tid & 127;
    const int sp = tid >> 7;  // MODE1: khalf; MODE2: X-plane / W-khalf
    const int xrow = r0 + srow;
    const bool xok = xrow < N;
    const bool wok = srow < NCOLS;

    const int lane = tid & 63;
    const int w = tid >> 6;
    const int wr = (w >> 1) * 64, wc = (w & 1) * 64;
    const int frow = lane & 15;
    const int fk = lane >> 4;
    const int q4 = lane >> 4;

    f32x4 acc[4][4];
#pragma unroll
    for (int i = 0; i < 4; ++i)
#pragma unroll
        for (int j = 0; j < 4; ++j) acc[i][j] = (f32x4){0.f, 0.f, 0.f, 0.f};

    const float4 z4 = make_float4(0.f, 0.f, 0.f, 0.f);
    const uint4 zz = make_uint4(0, 0, 0, 0);

    for (int kc = 0; kc < K / 32; ++kc) {
        if constexpr (MODE == 1) {
            const float* xp = Xf + (size_t)xrow * K + kc * 32 + sp * 16;
            const float* wp = Wf + (size_t)srow * K + kc * 32 + sp * 16;
            float4 xv[4], wv[4];
#pragma unroll
            for (int q = 0; q < 4; ++q) {
                xv[q] = xok ? *(const float4*)(xp + q * 4) : z4;
                wv[q] = wok ? *(const float4*)(wp + q * 4) : z4;
            }
            __syncthreads();
#pragma unroll
            for (int j = 0; j < 2; ++j) {
                int g = sp * 2 + j;
                *(uint4*)(Xs + srow * 64 + ((g) ^ (srow & 7)) * 8)     = pack_hi(xv[2 * j], xv[2 * j + 1]);
                *(uint4*)(Xs + srow * 64 + ((4 | g) ^ (srow & 7)) * 8) = pack_lo(xv[2 * j], xv[2 * j + 1]);
                *(uint4*)(Wt + srow * 64 + ((g) ^ (srow & 7)) * 8)     = pack_hi(wv[2 * j], wv[2 * j + 1]);
                *(uint4*)(Wt + srow * 64 + ((4 | g) ^ (srow & 7)) * 8) = pack_lo(wv[2 * j], wv[2 * j + 1]);
            }
            __syncthreads();
        } else {
            const unsigned short* xp = (sp ? Xlo : Xhi) + (size_t)xrow * K + kc * 32;
            const float* wp = Wf + (size_t)srow * K + kc * 32 + sp * 16;
            uint4 xg[4];
            float4 wv[4];
#pragma unroll
            for (int g = 0; g < 4; ++g) xg[g] = xok ? ((const uint4*)xp)[g] : zz;
#pragma unroll
            for (int q = 0; q < 4; ++q) wv[q] = wok ? *(const float4*)(wp + q * 4) : z4;
            __syncthreads();
#pragma unroll
            for (int g = 0; g < 4; ++g) {
                int p = ((sp << 2) | g) ^ (srow & 7);
                *(uint4*)(Xs + srow * 64 + p * 8) = xg[g];
            }
#pragma unroll
            for (int j = 0; j < 2; ++j) {
                int g = sp * 2 + j;
                *(uint4*)(Wt + srow * 64 + ((g) ^ (srow & 7)) * 8)     = pack_hi(wv[2 * j], wv[2 * j + 1]);
                *(uint4*)(Wt + srow * 64 + ((4 | g) ^ (srow & 7)) * 8) = pack_lo(wv[2 * j], wv[2 * j + 1]);
            }
            __syncthreads();
        }

        short8 ah[4], al[4], bh[4], bl[4];
#pragma unroll
        for (int ri = 0; ri < 4; ++ri) {
            int row = wr + ri * 16 + frow;
            ah[ri] = *(const short8*)(Xs + row * 64 + ((fk) ^ (row & 7)) * 8);
            al[ri] = *(const short8*)(Xs + row * 64 + ((4 | fk) ^ (row & 7)) * 8);
        }
#pragma unroll
        for (int ci = 0; ci < 4; ++ci) {
            int col = wc + ci * 16 + frow;
            bh[ci] = *(const short8*)(Wt + col * 64 + ((fk) ^ (col & 7)) * 8);
            bl[ci] = *(const short8*)(Wt + col * 64 + ((4 | fk) ^ (col & 7)) * 8);
        }
#pragma unroll
        for (int ri = 0; ri < 4; ++ri)
#pragma unroll
            for (int ci = 0; ci < 4; ++ci) {
                acc[ri][ci] = MFMA16(ah[ri], bh[ci], acc[ri][ci], 0, 0, 0);
                acc[ri][ci] = MFMA16(ah[ri], bl[ci], acc[ri][ci], 0, 0, 0);
                acc[ri][ci] = MFMA16(al[ri], bh[ci], acc[ri][ci], 0, 0, 0);
            }
    }

#pragma unroll
    for (int ci = 0; ci < 4; ++ci) {
        int col = wc + ci * 16 + frow;
        float bcol = (col < NCOLS) ? bias[col] : 0.f;
#pragma unroll
        for (int ri = 0; ri < 4; ++ri) {
            f32x4 v = acc[ri][ci];
#pragma unroll
            for (int reg = 0; reg < 4; ++reg) {
                int grow = r0 + wr + ri * 16 + q4 * 4 + reg;
                float val = v[reg] + bcol;
                if (grow < N && col < NCOLS) {
                    if constexpr (MODE == 1) {
                        val = fmaxf(val, 0.f);
                        Yhi[(size_t)grow * 128 + col] = (unsigned short)(__float_as_uint(val) >> 16);
                        Ylo[(size_t)grow * 128 + col] = (unsigned short)f2bf(val - hi_part(val));
                    } else {
                        Yf[(size_t)grow * 64 + col] = val;
                    }
                }
            }
        }
    }
}

// ---------------- hop GEMM: split-bf16 MFMA, dual-source, bf16-staged out ----
// Both halves output a bf16 [N,128] matrix (Yb0 = xnew_bf, Yb1 = hbf).
__global__ __launch_bounds__(256) void k_mm_bf(
    const unsigned short* __restrict__ Xhi0, const unsigned short* __restrict__ Xlo0, int nblk0,
    const unsigned short* __restrict__ Xhi1, const unsigned short* __restrict__ Xlo1,
    const unsigned short* __restrict__ Whi, const unsigned short* __restrict__ Wlo,
    const float* __restrict__ bias,
    unsigned short* __restrict__ Yb0, unsigned short* __restrict__ Yb1, int N,
    const float* __restrict__ dA0, float* __restrict__ oA0,
    const float* __restrict__ dB0, float* __restrict__ oB0,
    const float* __restrict__ dA1, float* __restrict__ oA1) {
    __shared__ unsigned short lds[128 * 128 + 1024];  // 34 KB (GEMM tiles / C-stage + dotbuf)
    unsigned short* Xs = lds;
    unsigned short* Wt = lds + 128 * 64;

    const int tid = threadIdx.x;
    const bool second = (int)blockIdx.x >= nblk0;
    const int bx = second ? (int)blockIdx.x - nblk0 : (int)blockIdx.x;
    const int r0 = bx * 128;
    const int srow = tid & 127;
    const int splane = tid >> 7;
    const unsigned short* Xp = second ? (splane ? Xlo1 : Xhi1) : (splane ? Xlo0 : Xhi0);
    const unsigned short* Wp = splane ? Wlo : Whi;
    unsigned short* Yb = second ? Yb1 : Yb0;
    const int xrow = r0 + srow;
    const bool xok = xrow < N;

    const int lane = tid & 63;
    const int w = tid >> 6;
    const int wr = (w >> 1) * 64, wc = (w & 1) * 64;
    const int frow = lane & 15;
    const int fk = lane >> 4;
    const int q4 = lane >> 4;

    f32x4 acc[4][4];
#pragma unroll
    for (int i = 0; i < 4; ++i)
#pragma unroll
        for (int j = 0; j < 4; ++j) acc[i][j] = (f32x4){0.f, 0.f, 0.f, 0.f};

    const uint4 zz = make_uint4(0, 0, 0, 0);
    for (int kc = 0; kc < 4; ++kc) {
        const uint4* xsrc = (const uint4*)(Xp + (size_t)xrow * 128 + kc * 32);
        const uint4* wsrc = (const uint4*)(Wp + (size_t)srow * 128 + kc * 32);
        uint4 xg[4], wg[4];
#pragma unroll
        for (int g = 0; g < 4; ++g) {
            xg[g] = xok ? xsrc[g] : zz;
            wg[g] = wsrc[g];
        }
        __syncthreads();
#pragma unroll
        for (int g = 0; g < 4; ++g) {
            int p = ((splane << 2) | g) ^ (srow & 7);
            *(uint4*)(Xs + srow * 64 + p * 8) = xg[g];
            *(uint4*)(Wt + srow * 64 + p * 8) = wg[g];
        }
        __syncthreads();

        short8 ah[4], al[4], bh[4], bl[4];
#pragma unroll
        for (int ri = 0; ri < 4; ++ri) {
            int row = wr + ri * 16 + frow;
            ah[ri] = *(const short8*)(Xs + row * 64 + (fk ^ (row & 7)) * 8);
            al[ri] = *(const short8*)(Xs + row * 64 + ((4 | fk) ^ (row & 7)) * 8);
        }
#pragma unroll
        for (int ci = 0; ci < 4; ++ci) {
            int col = wc + ci * 16 + frow;
            bh[ci] = *(const short8*)(Wt + col * 64 + (fk ^ (col & 7)) * 8);
            bl[ci] = *(const short8*)(Wt + col * 64 + ((4 | fk) ^ (col & 7)) * 8);
        }
#pragma unroll
        for (int ri = 0; ri < 4; ++ri)
#pragma unroll
            for (int ci = 0; ci < 4; ++ci) {
                acc[ri][ci] = MFMA16(ah[ri], bh[ci], acc[ri][ci], 0, 0, 0);
                acc[ri][ci] = MFMA16(ah[ri], bl[ci], acc[ri][ci], 0, 0, 0);
                acc[ri][ci] = MFMA16(al[ri], bh[ci], acc[ri][ci], 0, 0, 0);
            }
    }

    // ---- epilogue: bias + dots + bf16 LDS staging (dword-XOR swizzle) ----
    const float* dA = second ? dA1 : dA0;
    const float* dB = second ? nullptr : dB0;
    unsigned short* So = lds;                       // [128][128] bf16, swizzled
    float* dotbuf = (float*)(lds + 128 * 128);      // 2 KB: [2][128][2]

    float dotA[4][4] = {}, dotB[4][4] = {};
    __syncthreads();  // all waves done reading Xs/Wt
#pragma unroll
    for (int ci = 0; ci < 4; ++ci) {
        int col = wc + ci * 16 + frow;
        float bcol = bias[col];
        float dAc = dA ? dA[col] : 0.f;
        float dBc = dB ? dB[col] : 0.f;
#pragma unroll
        for (int ri = 0; ri < 4; ++ri) {
            f32x4 v = acc[ri][ci];
#pragma unroll
            for (int reg = 0; reg < 4; ++reg) {
                float val = v[reg] + bcol;
                int row = wr + ri * 16 + q4 * 4 + reg;
                int dw = (col >> 1) ^ ((row & 12) << 1);
                So[row * 128 + dw * 2 + (col & 1)] = (unsigned short)f2bf(val);
                dotA[ri][reg] = fmaf(val, dAc, dotA[ri][reg]);
                dotB[ri][reg] = fmaf(val, dBc, dotB[ri][reg]);
            }
        }
    }
#pragma unroll
    for (int m = 1; m < 16; m <<= 1)
#pragma unroll
        for (int ri = 0; ri < 4; ++ri)
#pragma unroll
            for (int reg = 0; reg < 4; ++reg) {
                dotA[ri][reg] += __shfl_xor(dotA[ri][reg], m, 64);
                dotB[ri][reg] += __shfl_xor(dotB[ri][reg], m, 64);
            }
    if (frow == 0) {
#pragma unroll
        for (int ri = 0; ri < 4; ++ri)
#pragma unroll
            for (int reg = 0; reg < 4; ++reg) {
                int rl = wr + ri * 16 + q4 * 4 + reg;
                dotbuf[(0 * 128 + rl) * 2 + (w & 1)] = dotA[ri][reg];
                dotbuf[(1 * 128 + rl) * 2 + (w & 1)] = dotB[ri][reg];
            }
    }
    __syncthreads();

    // cooperative full-line stores: 8 x uint4 per thread, rows dense
#pragma unroll
    for (int q = 0; q < 8; ++q) {
        int idx = q * 256 + tid;        // 0..2047
        int row = idx >> 4;
        int gc = idx & 15;
        int dwb = (gc * 4) ^ ((row & 12) << 1);
        uint4 vv = *(const uint4*)(So + row * 128 + dwb * 2);
        int grow = r0 + row;
        if (grow < N) *(uint4*)(Yb + (size_t)grow * 128 + gc * 8) = vv;
    }
    {
        int d = tid >> 7, rl = tid & 127;
        int grow = r0 + rl;
        float* oA = second ? oA1 : oA0;
        float* oB = second ? nullptr : oB0;
        if (grow < N) {
            float v = dotbuf[(d * 128 + rl) * 2] + dotbuf[(d * 128 + rl) * 2 + 1];
            if (d == 0) { if (oA) oA[grow] = v; }
            else        { if (oB) oB[grow] = v; }
        }
    }
}

// ---------------- aggregation: LDS-staged (t,w), 8-deep gather groups --------
__global__ __launch_bounds__(256) void k_agg(
    const unsigned short* __restrict__ xnb, const unsigned short* __restrict__ hbf,
    const float* __restrict__ x1a, const float* __restrict__ xa2a,
    const float* __restrict__ h1a, const int* __restrict__ rp,
    const int* __restrict__ ts,
    unsigned short* __restrict__ hhi, unsigned short* __restrict__ hlo, int N) {
    __shared__ uint2 ew[4][64];
    const int wid = threadIdx.x >> 6;
    const int lane = threadIdx.x & 63;
    const int u = blockIdx.x * 4 + wid;
    if (u >= N) return;  // no barriers below; per-wave LDS slice only
    const int l2 = lane << 1;
    float x1u = x1a[u];
    float w2 = expf(lrelu02(x1u + xa2a[u]));
    float2 xr = bf2f2(*(const unsigned int*)(xnb + (size_t)u * 128 + l2));
    float accx = w2 * xr.x, accy = w2 * xr.y;
    float div = w2;
    int p0 = rp[u], p1 = rp[u + 1];
    for (int base = p0; base < p1; base += 64) {
        int e = base + lane;
        uint2 pk = make_uint2(0u, 0u);  // t=0, w=0 pad: zero contribution
        if (e < p1) {
            int tv = ts[e];
            pk.x = (unsigned int)tv;
            pk.y = __float_as_uint(expf(lrelu02(x1u + h1a[tv])));
        }
        ew[wid][lane] = pk;
        int m = p1 - base; if (m > 64) m = 64;
        int m8 = (m + 7) & ~7;
        for (int j = 0; j < m8; j += 8) {
            uint2 q[8];
#pragma unroll
            for (int k = 0; k < 8; ++k) q[k] = ew[wid][j + k];
            unsigned int hv[8];
#pragma unroll
            for (int k = 0; k < 8; ++k)
                hv[k] = *(const unsigned int*)(hbf + (size_t)q[k].x * 128 + l2);
#pragma unroll
            for (int k = 0; k < 8; ++k) {
                float ww = __uint_as_float(q[k].y);
                float2 f = bf2f2(hv[k]);
                accx = fmaf(ww, f.x, accx);
                accy = fmaf(ww, f.y, accy);
                div += ww;
            }
        }
    }
    float ox = accx / div, oy = accy / div;
    ox = ox > 0.f ? ox : expf(ox) - 1.f;
    oy = oy > 0.f ? oy : expf(oy) - 1.f;
    unsigned int hx = __float_as_uint(ox), hy = __float_as_uint(oy);
    *(unsigned int*)(hhi + (size_t)u * 128 + l2) = (hx >> 16) | (hy & 0xffff0000u);
    float lox = ox - __uint_as_float(hx & 0xffff0000u);
    float loy = oy - __uint_as_float(hy & 0xffff0000u);
    *(unsigned int*)(hlo + (size_t)u * 128 + l2) = f2bf(lox) | (f2bf(loy) << 16);
}

// ---------------- launch ----------------
extern "C" void kernel_launch(void* const* d_in, const int* in_sizes, int n_in,
                              void* d_out, int out_size, void* d_ws, size_t ws_size,
                              hipStream_t stream) {
    const float* x_in = (const float*)d_in[0];
    const int*   s    = (const int*)d_in[1];
    const int*   t    = (const int*)d_in[2];
    const float* fc1W = (const float*)d_in[3];
    const float* fc1b = (const float*)d_in[4];
    const float* fcsW = (const float*)d_in[5];
    const float* fcsb = (const float*)d_in[6];
    const float* a1   = (const float*)d_in[7];
    const float* a2   = (const float*)d_in[8];
    const float* fc2W = (const float*)d_in[9];
    const float* fc2b = (const float*)d_in[10];

    const int N = in_sizes[0] / 256;  // 50000
    const int E = in_sizes[1];        // 800000
    const int G = (N + 255) / 256;
    const int NB = (N + 127) / 128;   // 391

    char* ws = (char*)d_ws;
    size_t off = 0;
    auto alloc = [&](size_t bytes) -> void* {
        void* p = ws + off;
        off += (bytes + 255) & ~(size_t)255;
        return p;
    };
    unsigned short* xbuf_hi = (unsigned short*)alloc((size_t)N * 128 * 2);
    unsigned short* xbuf_lo = (unsigned short*)alloc((size_t)N * 128 * 2);
    unsigned short* h_hi    = (unsigned short*)alloc((size_t)N * 128 * 2);
    unsigned short* h_lo    = (unsigned short*)alloc((size_t)N * 128 * 2);
    unsigned short* xnb     = (unsigned short*)alloc((size_t)N * 128 * 2);  // xnew bf16
    unsigned short* hbf     = (unsigned short*)alloc((size_t)N * 128 * 2);
    unsigned short* Whi = (unsigned short*)alloc((size_t)10 * 128 * 128 * 2);
    unsigned short* Wlo = (unsigned short*)alloc((size_t)10 * 128 * 128 * 2);
    float* x1a  = (float*)alloc((size_t)N * 4);
    float* xa2a = (float*)alloc((size_t)N * 4);
    float* h1a  = (float*)alloc((size_t)N * 4);
    int* row_ptr  = (int*)alloc((size_t)(N + 1) * 4);
    int* cnt      = (int*)alloc((size_t)N * 4);
    int* bsums    = (int*)alloc((size_t)256 * 4);
    int* t_sorted = (int*)alloc((size_t)E * 4);

    // CSR build
    hipMemsetAsync(cnt, 0, (size_t)N * 4, stream);
    k_count<<<(E + 255) / 256, 256, 0, stream>>>(s, cnt, E);
    k_scan1<<<G, 256, 0, stream>>>(cnt, bsums, N);
    k_scan2<<<1, 256, 0, stream>>>(bsums, G);
    k_scan3<<<G, 256, 0, stream>>>(cnt, bsums, row_ptr, N);
    hipMemsetAsync(cnt, 0, (size_t)N * 4, stream);
    k_scatter<<<(E + 255) / 256, 256, 0, stream>>>(s, t, row_ptr, cnt, t_sorted, E);

    // W splits for hop weights
    k_wsplit<<<(10 * 128 * 128 + 255) / 256, 256, 0, stream>>>(fcsW, Whi, Wlo, 10 * 128 * 128);

    // fc1 + relu -> split planes (MFMA)
    k_mmfc<1><<<NB, 256, 0, stream>>>(x_in, nullptr, nullptr, fc1W, fc1b,
                                      nullptr, xbuf_hi, xbuf_lo, N);

    // hops
    const unsigned short* hs_hi = xbuf_hi;
    const unsigned short* hs_lo = xbuf_lo;
    for (int i = 0; i < 10; ++i) {
        const unsigned short* Wh = Whi + (size_t)i * 128 * 128;
        const unsigned short* Wl = Wlo + (size_t)i * 128 * 128;
        const float* b   = fcsb + (size_t)i * 128;
        const float* a1i = a1 + (size_t)i * 128;
        const float* a2i = a2 + (size_t)i * 128;
        k_mm_bf<<<2 * NB, 256, 0, stream>>>(xbuf_hi, xbuf_lo, NB, hs_hi, hs_lo,
                                            Wh, Wl, b, xnb, hbf, N,
                                            a1i, x1a, a2i, xa2a, a2i, h1a);
        k_agg<<<(N + 3) / 4, 256, 0, stream>>>(xnb, hbf, x1a, xa2a, h1a,
                                               row_ptr, t_sorted, h_hi, h_lo, N);
        hs_hi = h_hi; hs_lo = h_lo;
    }

    // fc2 (MFMA, planes in, fp32 out)
    k_mmfc<2><<<NB, 256, 0, stream>>>(nullptr, h_hi, h_lo, fc2W, fc2b,
                                      (float*)d_out, nullptr, nullptr, N);
}